// Round 3
// baseline (151.016 us; speedup 1.0000x reference)
//
#include <hip/hip_runtime.h>

// Round 12: FUSE gate+attn into one kernel (flag-based producer/consumer).
// Accounting: TWO 256MiB poison fills (~86us) sit in the timed region
// (dispatch IDs 11 apart); controllable budget ~29us across 3 launches.
// R10/R11 nulls => inner loops fine; remaining waste is pipeline structure:
// 2 launch gaps, gate-drain/attn-ramp serialization, q HBM round-trip.
// Design:
//  - block (b,seg): gate for tokens seg*64..+64 of batch b, then attn for
//    q-tile seg of batch b. dim3(128,8): deps point to lower linear IDs
//    (seg=0 never waits) => practically deadlock-free; all 8 blocks of a
//    batch land on XCD b%8 (shared-L2 safety net).
//  - q stays in LDS (own block is sole consumer): ks/vs/qs/ps alias into
//    the dead weights region; LDS still 51KB -> 3 blocks/CU at (256,3).
//  - diagonal k/v tile staged to LDS from regs, processed FIRST (hides
//    flag spin; no-max softmax is order-independent).
//  - k/v handoff: relaxed agent-scope atomic stores (write-through to the
//    coherent point) + release/acquire agent flag; consumer loads are
//    first-touch => no stale-L2 hazard, no cache-wide flushes.
//  - seg==7 k/v consumed by nobody: skip global stores + flag.
//  - prep also zeroes the 1024 flags each replay (stream-ordered).

#define BB 128
#define TB 512
#define CC 128
#define HH 64

static constexpr float SEXP2 =
    (float)(0.088388347648318447 * 1.4426950408889634);  // C^-0.5 * log2(e)

typedef __attribute__((ext_vector_type(8))) short bf16x8;
typedef __attribute__((ext_vector_type(8))) unsigned short u16x8;
typedef __attribute__((ext_vector_type(4))) float f32x4;

__device__ inline unsigned short f2bf(float f) {
    union { float f; unsigned u; } x; x.f = f;
    unsigned r = x.u + 0x7fff + ((x.u >> 16) & 1);   // RNE
    return (unsigned short)(r >> 16);
}
__device__ inline bf16x8 pack8(float4 a, float4 b) {
    bf16x8 o;
    o[0] = (short)f2bf(a.x); o[1] = (short)f2bf(a.y);
    o[2] = (short)f2bf(a.z); o[3] = (short)f2bf(a.w);
    o[4] = (short)f2bf(b.x); o[5] = (short)f2bf(b.y);
    o[6] = (short)f2bf(b.z); o[7] = (short)f2bf(b.w);
    return o;
}

// ---- weight transpose+convert + flag zeroing ----
__global__ void prep_weights(const float* __restrict__ Wg, const float* __restrict__ Wk,
                             const float* __restrict__ Wq, const float* __restrict__ Wv,
                             unsigned short* __restrict__ WgT, unsigned short* __restrict__ WkT,
                             unsigned short* __restrict__ WqT, unsigned short* __restrict__ WvT,
                             int* __restrict__ flags)
{
    int idx = blockIdx.x * 256 + threadIdx.x;        // 0..40959
    if (idx < 1024) flags[idx] = 0;                  // re-zero every replay
    if (idx < 16384) {                               // Wg 128x128
        int n = idx >> 7, k = idx & 127;
        WgT[idx] = f2bf(Wg[k * CC + n]);
    } else {
        int j = idx - 16384;                         // 3 x (64x128)
        int mtx = j >> 13;
        int r = j & 8191;
        int n = r >> 7, k = r & 127;
        const float* W = (mtx == 0) ? Wk : (mtx == 1) ? Wq : Wv;
        unsigned short* WT = (mtx == 0) ? WkT : (mtx == 1) ? WqT : WvT;
        WT[r] = f2bf(W[k * HH + n]);
    }
}

// ---- one attention k-tile: frags from LDS, S^T mfma, exp2, rowsum+PV ----
__device__ __forceinline__ void attn_tile(
    const unsigned short* ks_, const unsigned short* vs_, unsigned short* ps_,
    bf16x8 aq0, bf16x8 aq1, bf16x8 ones, bool diag,
    f32x4* o, f32x4& lacc, int wv, int l15, int quad)
{
    bf16x8 bk0[4], bk1[4], bv0[4], bv1[4];
#pragma unroll
    for (int nt = 0; nt < 4; ++nt) {
        bk0[nt] = *(const bf16x8*)(ks_ + (16 * nt + l15) * 72 + quad * 8);
        bk1[nt] = *(const bf16x8*)(ks_ + (16 * nt + l15) * 72 + 32 + quad * 8);
        bv0[nt] = *(const bf16x8*)(vs_ + (16 * nt + l15) * 72 + quad * 8);
        bv1[nt] = *(const bf16x8*)(vs_ + (16 * nt + l15) * 72 + 32 + quad * 8);
    }

    f32x4 s[4];
#pragma unroll
    for (int nt = 0; nt < 4; ++nt) {
        f32x4 z = (f32x4){0.f, 0.f, 0.f, 0.f};
        z = __builtin_amdgcn_mfma_f32_16x16x32_bf16(bk0[nt], aq0, z, 0, 0, 0);
        z = __builtin_amdgcn_mfma_f32_16x16x32_bf16(bk1[nt], aq1, z, 0, 0, 0);
        s[nt] = z;
    }

    unsigned short* pr = ps_ + (16 * wv + l15) * 76;
#pragma unroll
    for (int nt = 0; nt < 4; ++nt) {
        float p[4];
#pragma unroll
        for (int r = 0; r < 4; ++r) {
            float sv = s[nt][r] * SEXP2;
            if (diag && (16 * nt + 4 * quad + r) > (16 * wv + l15)) sv = -1e30f;
            p[r] = exp2f(sv);
        }
        ushort4 h;
        h.x = f2bf(p[0]); h.y = f2bf(p[1]); h.z = f2bf(p[2]); h.w = f2bf(p[3]);
        *(ushort4*)(pr + 16 * nt + 4 * quad) = h;
    }

    bf16x8 ap0 = *(const bf16x8*)(pr + quad * 8);
    bf16x8 ap1 = *(const bf16x8*)(pr + 32 + quad * 8);
    lacc = __builtin_amdgcn_mfma_f32_16x16x32_bf16(ap0, ones, lacc, 0, 0, 0);
    lacc = __builtin_amdgcn_mfma_f32_16x16x32_bf16(ap1, ones, lacc, 0, 0, 0);
#pragma unroll
    for (int nt = 0; nt < 4; ++nt) {
        o[nt] = __builtin_amdgcn_mfma_f32_16x16x32_bf16(ap0, bv0[nt], o[nt], 0, 0, 0);
        o[nt] = __builtin_amdgcn_mfma_f32_16x16x32_bf16(ap1, bv1[nt], o[nt], 0, 0, 0);
    }
}

__global__ __launch_bounds__(256, 3) void fused_kernel(
    const float* __restrict__ x, const float* __restrict__ bg,
    const unsigned short* __restrict__ WgT, const unsigned short* __restrict__ WkT,
    const unsigned short* __restrict__ WqT, const unsigned short* __restrict__ WvT,
    unsigned short* __restrict__ ko, unsigned short* __restrict__ vto,
    int* __restrict__ flags, float* __restrict__ out)
{
    // 51 KB. Phase G1: rows 0..127 = WgT, rows 128..191 free (slice alias).
    // Phase G2: rows 0..191 = Wk/Wq/Wv. Phase A: ks/vs/qs/ps alias (18688 u16).
    __shared__ unsigned short wlds[192 * 136];
    unsigned short* ks_ = wlds;              // 64*72
    unsigned short* vs_ = wlds + 4608;       // 64*72
    unsigned short* qs_ = wlds + 9216;       // 64*72
    unsigned short* ps_ = wlds + 13824;      // 64*76

    const int tid  = threadIdx.x;
    const int wv   = tid >> 6;
    const int lane = tid & 63;
    const int l15  = lane & 15;
    const int quad = lane >> 4;
    const int b    = blockIdx.x;             // 0..127
    const int seg  = blockIdx.y;             // 0..7  (gate tile == attn q-tile)
    const int t0   = seg * 64;
    const int R0   = b * 512 + t0;           // global token row
    const int row0 = R0 + 16 * wv;
    const size_t base = (size_t)b * TB * HH;
    const int fl = b * 8 + seg;

    // ================= GATE PHASE =================
#pragma unroll
    for (int it = 0; it < 8; ++it) {
        int idx = tid + 256 * it;
        int r = idx >> 4, c8 = idx & 15;
        *(u16x8*)(wlds + r * 136 + c8 * 8) = *(const u16x8*)(WgT + r * 128 + c8 * 8);
    }

    bf16x8 bx[4];
#pragma unroll
    for (int kc = 0; kc < 4; ++kc) {
        const float* p = x + (size_t)(row0 + l15) * CC + kc * 32 + quad * 8;
        float4 a = *(const float4*)p;
        float4 c = *(const float4*)(p + 4);
        bx[kc] = pack8(a, c);
    }

    __syncthreads();                                 // WgT staged

    f32x4 acc[8];
#pragma unroll
    for (int nt = 0; nt < 8; ++nt) acc[nt] = (f32x4){0.f, 0.f, 0.f, 0.f};
#pragma unroll
    for (int nt = 0; nt < 8; ++nt)
#pragma unroll
        for (int kc = 0; kc < 4; ++kc) {
            bf16x8 aw = *(const bf16x8*)(wlds + (16 * nt + l15) * 136 + kc * 32 + quad * 8);
            acc[nt] = __builtin_amdgcn_mfma_f32_16x16x32_bf16(aw, bx[kc], acc[nt], 0, 0, 0);
        }

    // sigmoid + per-kc slice round-trip -> xg B-frags (slice in rows 128..191)
    unsigned short* sl = wlds + 128 * 136 + wv * (16 * 40);
    bf16x8 bxg[4];
#pragma unroll
    for (int kc = 0; kc < 4; ++kc) {
#pragma unroll
        for (int half = 0; half < 2; ++half) {
            int nt = 2 * kc + half;
            float4 bgv = *(const float4*)(bg + 16 * nt + 4 * quad);
            float4 xe = *(const float4*)(x + (size_t)(row0 + l15) * CC + 16 * nt + 4 * quad);
            float e0 = __expf(-(acc[nt][0] + bgv.x));
            float e1 = __expf(-(acc[nt][1] + bgv.y));
            float e2 = __expf(-(acc[nt][2] + bgv.z));
            float e3 = __expf(-(acc[nt][3] + bgv.w));
            ushort4 o;
            o.x = f2bf(xe.x * __builtin_amdgcn_rcpf(1.f + e0));
            o.y = f2bf(xe.y * __builtin_amdgcn_rcpf(1.f + e1));
            o.z = f2bf(xe.z * __builtin_amdgcn_rcpf(1.f + e2));
            o.w = f2bf(xe.w * __builtin_amdgcn_rcpf(1.f + e3));
            *(ushort4*)(sl + l15 * 40 + 16 * half + 4 * quad) = o;
        }
        bxg[kc] = *(const bf16x8*)(sl + l15 * 40 + quad * 8);
    }

    __syncthreads();                                 // Wg frag + slice reads done

    // restage Wk/Wq/Wv (rows 0..191)
#pragma unroll
    for (int it = 0; it < 12; ++it) {
        int idx = tid + 256 * it;
        int r = idx >> 4, c8 = idx & 15;
        const unsigned short* src = (r < 64) ? (WkT + r * 128)
                                  : (r < 128) ? (WqT + (r - 64) * 128)
                                              : (WvT + (r - 128) * 128);
        *(u16x8*)(wlds + r * 136 + c8 * 8) = *(const u16x8*)(src + c8 * 8);
    }
    __syncthreads();

    // k / q / v projections, all held in regs (wlds dies after this)
    f32x4 pk[4], pq[4], pv[4];
#pragma unroll
    for (int nt = 0; nt < 4; ++nt) {
        pk[nt] = (f32x4){0.f, 0.f, 0.f, 0.f};
        pq[nt] = (f32x4){0.f, 0.f, 0.f, 0.f};
        pv[nt] = (f32x4){0.f, 0.f, 0.f, 0.f};
    }
#pragma unroll
    for (int nt = 0; nt < 4; ++nt)
#pragma unroll
        for (int kc = 0; kc < 4; ++kc) {
            bf16x8 aw = *(const bf16x8*)(wlds + (16 * nt + l15) * 136 + kc * 32 + quad * 8);
            pk[nt] = __builtin_amdgcn_mfma_f32_16x16x32_bf16(aw, bxg[kc], pk[nt], 0, 0, 0);
        }
#pragma unroll
    for (int nt = 0; nt < 4; ++nt)
#pragma unroll
        for (int kc = 0; kc < 4; ++kc) {
            bf16x8 aw = *(const bf16x8*)(wlds + (64 + 16 * nt + l15) * 136 + kc * 32 + quad * 8);
            pq[nt] = __builtin_amdgcn_mfma_f32_16x16x32_bf16(aw, bxg[kc], pq[nt], 0, 0, 0);
        }
#pragma unroll
    for (int nt = 0; nt < 4; ++nt)
#pragma unroll
        for (int kc = 0; kc < 4; ++kc) {
            bf16x8 aw = *(const bf16x8*)(wlds + (128 + 16 * nt + l15) * 136 + kc * 32 + quad * 8);
            pv[nt] = __builtin_amdgcn_mfma_f32_16x16x32_bf16(aw, bxg[kc], pv[nt], 0, 0, 0);
        }

    __syncthreads();                                 // all wlds reads done -> alias

    // ---- G3: global k/v (write-through agent atomics) + LDS diag q/k/v ----
    const int m16 = 16 * wv + l15;                   // token within tile
    if (seg < 7) {                                   // tile 7 has no consumers
#pragma unroll
        for (int nt = 0; nt < 4; ++nt) {
            unsigned long long v64 =
                (unsigned long long)f2bf(pk[nt][0]) |
                ((unsigned long long)f2bf(pk[nt][1]) << 16) |
                ((unsigned long long)f2bf(pk[nt][2]) << 32) |
                ((unsigned long long)f2bf(pk[nt][3]) << 48);
            __hip_atomic_store(
                (unsigned long long*)(ko + (size_t)(R0 + m16) * HH + 16 * nt + 4 * quad),
                v64, __ATOMIC_RELAXED, __HIP_MEMORY_SCOPE_AGENT);
        }
#pragma unroll
        for (int nt = 0; nt < 4; ++nt)
#pragma unroll
            for (int r = 0; r < 4; ++r)
                __hip_atomic_store(
                    vto + base + (size_t)(16 * nt + 4 * quad + r) * TB + t0 + m16,
                    f2bf(pv[nt][r]), __ATOMIC_RELAXED, __HIP_MEMORY_SCOPE_AGENT);
    }
#pragma unroll
    for (int nt = 0; nt < 4; ++nt) {
        ushort4 hk, hq;
        hk.x = f2bf(pk[nt][0]); hk.y = f2bf(pk[nt][1]);
        hk.z = f2bf(pk[nt][2]); hk.w = f2bf(pk[nt][3]);
        hq.x = f2bf(pq[nt][0]); hq.y = f2bf(pq[nt][1]);
        hq.z = f2bf(pq[nt][2]); hq.w = f2bf(pq[nt][3]);
        *(ushort4*)(ks_ + m16 * 72 + 16 * nt + 4 * quad) = hk;
        *(ushort4*)(qs_ + m16 * 72 + 16 * nt + 4 * quad) = hq;
#pragma unroll
        for (int r = 0; r < 4; ++r)
            vs_[(16 * nt + 4 * quad + r) * 72 + m16] = f2bf(pv[nt][r]);
    }

    __syncthreads();   // diag LDS visible; also drains the global k/v stores

    if (seg < 7 && tid == 0)
        __hip_atomic_store(&flags[fl], 1, __ATOMIC_RELEASE, __HIP_MEMORY_SCOPE_AGENT);

    // ================= ATTN PHASE =================
    bf16x8 ones;
#pragma unroll
    for (int i = 0; i < 8; ++i) ones[i] = (short)0x3F80;   // bf16 1.0

    const unsigned short* qr = qs_ + (16 * wv + l15) * 72;
    bf16x8 aq0 = *(const bf16x8*)(qr + quad * 8);
    bf16x8 aq1 = *(const bf16x8*)(qr + 32 + quad * 8);

    f32x4 o[4], lacc;
#pragma unroll
    for (int nt = 0; nt < 4; ++nt) o[nt] = (f32x4){0.f, 0.f, 0.f, 0.f};
    lacc = (f32x4){0.f, 0.f, 0.f, 0.f};

    // diagonal tile first (already in LDS, hides flag spin for earlier tiles)
    attn_tile(ks_, vs_, ps_, aq0, aq1, ones, true, o, lacc, wv, l15, quad);

    const int r0 = tid >> 3, c8v = (tid & 7) * 8;
    const int r1 = r0 + 32;
    for (int kt = 0; kt < seg; ++kt) {
        if (tid == 0) {
            while (__hip_atomic_load(&flags[b * 8 + kt], __ATOMIC_ACQUIRE,
                                     __HIP_MEMORY_SCOPE_AGENT) == 0)
                __builtin_amdgcn_s_sleep(2);
        }
        __syncthreads();                 // flag seen + prev tile frag reads done

        bf16x8 kr0 = *(const bf16x8*)(ko + base + (size_t)(kt * 64 + r0) * HH + c8v);
        bf16x8 kr1 = *(const bf16x8*)(ko + base + (size_t)(kt * 64 + r1) * HH + c8v);
        bf16x8 vr0 = *(const bf16x8*)(vto + base + (size_t)r0 * TB + kt * 64 + c8v);
        bf16x8 vr1 = *(const bf16x8*)(vto + base + (size_t)r1 * TB + kt * 64 + c8v);
        *(bf16x8*)(ks_ + r0 * 72 + c8v) = kr0;
        *(bf16x8*)(ks_ + r1 * 72 + c8v) = kr1;
        *(bf16x8*)(vs_ + r0 * 72 + c8v) = vr0;
        *(bf16x8*)(vs_ + r1 * 72 + c8v) = vr1;
        __syncthreads();

        attn_tile(ks_, vs_, ps_, aq0, aq1, ones, false, o, lacc, wv, l15, quad);
    }

    // epilogue
    float inv[4];
#pragma unroll
    for (int r = 0; r < 4; ++r) inv[r] = __builtin_amdgcn_rcpf(lacc[r]);
#pragma unroll
    for (int nt = 0; nt < 4; ++nt)
#pragma unroll
        for (int r = 0; r < 4; ++r)
            out[base + (size_t)(t0 + 16 * wv + quad * 4 + r) * HH + 16 * nt + l15] =
                o[nt][r] * inv[r];
}

extern "C" void kernel_launch(void* const* d_in, const int* in_sizes, int n_in,
                              void* d_out, int out_size, void* d_ws, size_t ws_size,
                              hipStream_t stream) {
    const float* x  = (const float*)d_in[0];
    const float* Wg = (const float*)d_in[1];
    const float* bg = (const float*)d_in[2];
    const float* Wk = (const float*)d_in[3];
    const float* Wq = (const float*)d_in[4];
    const float* Wv = (const float*)d_in[5];
    float* out = (float*)d_out;

    unsigned short* ws = (unsigned short*)d_ws;
    const size_t BTH = (size_t)BB * TB * HH;   // 4,194,304
    unsigned short* ko  = ws;                  // k bf16 [B*T][H]
    unsigned short* vto = ws + BTH;            // vT bf16 [B][H][T]
    unsigned short* WgT = ws + 2 * BTH;        // 128x128
    unsigned short* WkT = WgT + 16384;         // 64x128 each
    unsigned short* WqT = WkT + 8192;
    unsigned short* WvT = WqT + 8192;
    int* flags = (int*)(WvT + 8192);           // 1024 flags (4KB), ~16.9MB total

    hipLaunchKernelGGL(prep_weights, dim3(160), dim3(256), 0, stream,
                       Wg, Wk, Wq, Wv, WgT, WkT, WqT, WvT, flags);
    hipLaunchKernelGGL(fused_kernel, dim3(BB, 8), dim3(256), 0, stream,
                       x, bg, WgT, WkT, WqT, WvT, ko, vto, flags, out);
}

// Round 6
// 116.025 us; speedup vs baseline: 1.3016x; 1.3016x over previous
//
#include <hip/hip_runtime.h>

// Round 15: REVERT to proven split kernels (R11 structure) + SINGLE-x-READ gate.
// R13/R14 post-mortem: identical absmax 2.84375 across two DIFFERENT attn
// orientations => out didn't depend on attn at all => consumers read zeros:
// plain-store + agent-fence + grid.sync does NOT deliver cross-XCD data on
// gfx950 (producer L2 dirty lines not written back; R12's atomic stores were
// the only working handoff, and they cost ~what fusion saves). Fusion dropped.
// This round's change (gate only, attn/prep = R11 verbatim):
//  - x is read ONCE (fp32, for bx MFMA frags); the bf16 x-tile is also stashed
//    in LDS rows 128..191 (dead until restage). Epilogue reads bf16 x from
//    LDS and writes xg IN PLACE (same-wave FIFO round-trip, proven pattern
//    since R9's slice). bxg frags then read from the same region.
//  - saves 33.5MB HBM (~5.3us) + 8 float4 global loads/lane.
//  - numeric: one extra bf16 rounding of x in the gate product; absmax
//    headroom 7x (0.0078 vs 0.0569 threshold).

#define BB 128
#define TB 512
#define CC 128
#define HH 64

static constexpr float SCALE = 0.088388347648318447f;  // C^-0.5 (NOT H^-0.5)

typedef __attribute__((ext_vector_type(8))) short bf16x8;
typedef __attribute__((ext_vector_type(8))) unsigned short u16x8;
typedef __attribute__((ext_vector_type(4))) float f32x4;

__device__ inline unsigned short f2bf(float f) {
    union { float f; unsigned u; } x; x.f = f;
    unsigned r = x.u + 0x7fff + ((x.u >> 16) & 1);   // RNE
    return (unsigned short)(r >> 16);
}
__device__ inline float bf2f(unsigned short h) {
    union { unsigned u; float f; } x; x.u = ((unsigned)h) << 16;
    return x.f;
}
__device__ inline bf16x8 pack8(float4 a, float4 b) {
    bf16x8 o;
    o[0] = (short)f2bf(a.x); o[1] = (short)f2bf(a.y);
    o[2] = (short)f2bf(a.z); o[3] = (short)f2bf(a.w);
    o[4] = (short)f2bf(b.x); o[5] = (short)f2bf(b.y);
    o[6] = (short)f2bf(b.z); o[7] = (short)f2bf(b.w);
    return o;
}

// ---- weight transpose+convert: WT[n][k] = bf16(W[k][n]) ----
__global__ void prep_weights(const float* __restrict__ Wg, const float* __restrict__ Wk,
                             const float* __restrict__ Wq, const float* __restrict__ Wv,
                             unsigned short* __restrict__ WgT, unsigned short* __restrict__ WkT,
                             unsigned short* __restrict__ WqT, unsigned short* __restrict__ WvT)
{
    int idx = blockIdx.x * 256 + threadIdx.x;        // 0..40959
    if (idx < 16384) {                               // Wg 128x128
        int n = idx >> 7, k = idx & 127;
        WgT[idx] = f2bf(Wg[k * CC + n]);
    } else {
        int j = idx - 16384;                         // 3 x (64x128)
        int mtx = j >> 13;
        int r = j & 8191;
        int n = r >> 7, k = r & 127;
        const float* W = (mtx == 0) ? Wk : (mtx == 1) ? Wq : Wv;
        unsigned short* WT = (mtx == 0) ? WkT : (mtx == 1) ? WqT : WvT;
        WT[r] = f2bf(W[k * HH + n]);
    }
}

__global__ __launch_bounds__(256, 3) void gate_qkv_kernel(
    const float* __restrict__ x, const float* __restrict__ bg,
    const unsigned short* __restrict__ WgT, const unsigned short* __restrict__ WkT,
    const unsigned short* __restrict__ WqT, const unsigned short* __restrict__ WvT,
    unsigned short* __restrict__ qo, unsigned short* __restrict__ ko,
    unsigned short* __restrict__ vto)
{
    // 51 KB: rows 0..127 = WgT (phase 1) / Wk,Wq,Wv rows 0..191 (phase 2).
    // rows 128..191 in phase 1 = bf16 x-tile [64 tok][128 feat], stride 136;
    // xg overwrites it in place during the sigmoid epilogue.
    __shared__ unsigned short wlds[192 * 136];
    unsigned short* xls = wlds + 128 * 136;

    const int tid  = threadIdx.x;
    const int wv   = tid >> 6;
    const int lane = tid & 63;
    const int l15  = lane & 15;
    const int quad = lane >> 4;
    const int R0   = blockIdx.x * 64;
    const int row0 = R0 + 16 * wv;

    // ---- stage WgT (128 rows x 16 chunks) ----
#pragma unroll
    for (int it = 0; it < 8; ++it) {
        int idx = tid + 256 * it;                    // 0..2047
        int r = idx >> 4, c8 = idx & 15;
        *(u16x8*)(wlds + r * 136 + c8 * 8) = *(const u16x8*)(WgT + r * 128 + c8 * 8);
    }

    // ---- x: single global read -> bx regs + bf16 x-tile into LDS ----
    unsigned short* xrow = xls + (16 * wv + l15) * 136;   // wave-private row
    bf16x8 bx[4];
#pragma unroll
    for (int kc = 0; kc < 4; ++kc) {
        const float* p = x + (size_t)(row0 + l15) * CC + kc * 32 + quad * 8;
        float4 a = *(const float4*)p;
        float4 c = *(const float4*)(p + 4);
        bx[kc] = pack8(a, c);
        *(bf16x8*)(xrow + kc * 32 + quad * 8) = bx[kc];
    }

    __syncthreads();                                 // WgT staged

    // ---- gate GEMM (frags from LDS) ----
    f32x4 acc[8];
#pragma unroll
    for (int nt = 0; nt < 8; ++nt) acc[nt] = (f32x4){0.f, 0.f, 0.f, 0.f};

#pragma unroll
    for (int nt = 0; nt < 8; ++nt) {
#pragma unroll
        for (int kc = 0; kc < 4; ++kc) {
            bf16x8 aw = *(const bf16x8*)(wlds + (16 * nt + l15) * 136 + kc * 32 + quad * 8);
            acc[nt] = __builtin_amdgcn_mfma_f32_16x16x32_bf16(aw, bx[kc], acc[nt], 0, 0, 0);
        }
    }

    // ---- sigmoid epilogue: x from LDS (bf16), xg in place, bxg frags ----
    bf16x8 bxg[4];
#pragma unroll
    for (int kc = 0; kc < 4; ++kc) {
#pragma unroll
        for (int half = 0; half < 2; ++half) {
            int nt = 2 * kc + half;
            float4 bgv = *(const float4*)(bg + 16 * nt + 4 * quad);
            // feature f = 16*nt + 4*quad + r = 32*kc + 16*half + 4*quad + r
            ushort4 xb = *(const ushort4*)(xrow + kc * 32 + 16 * half + 4 * quad);
            float e0 = __expf(-(acc[nt][0] + bgv.x));
            float e1 = __expf(-(acc[nt][1] + bgv.y));
            float e2 = __expf(-(acc[nt][2] + bgv.z));
            float e3 = __expf(-(acc[nt][3] + bgv.w));
            ushort4 o;
            o.x = f2bf(bf2f(xb.x) * __builtin_amdgcn_rcpf(1.f + e0));
            o.y = f2bf(bf2f(xb.y) * __builtin_amdgcn_rcpf(1.f + e1));
            o.z = f2bf(bf2f(xb.z) * __builtin_amdgcn_rcpf(1.f + e2));
            o.w = f2bf(bf2f(xb.w) * __builtin_amdgcn_rcpf(1.f + e3));
            *(ushort4*)(xrow + kc * 32 + 16 * half + 4 * quad) = o;   // in place
        }
        // same-wave FIFO LDS: all 32 features of chunk kc written above
        bxg[kc] = *(const bf16x8*)(xrow + kc * 32 + quad * 8);
    }

    __syncthreads();                                 // Wg frag + xg reads done

    // ---- restage Wk/Wq/Wv (192 rows; overwrites x/xg region — bxg in regs) ----
#pragma unroll
    for (int it = 0; it < 12; ++it) {
        int idx = tid + 256 * it;                    // 0..3071
        int r = idx >> 4, c8 = idx & 15;
        const unsigned short* src = (r < 64) ? (WkT + r * 128)
                                  : (r < 128) ? (WqT + (r - 64) * 128)
                                              : (WvT + (r - 128) * 128);
        *(u16x8*)(wlds + r * 136 + c8 * 8) = *(const u16x8*)(src + c8 * 8);
    }
    __syncthreads();

    // ---- q/k/v projections (frags from LDS) ----
    const int b = R0 >> 9, t0 = R0 & 511;
    const int m = 16 * wv + l15;                     // token within block
#pragma unroll
    for (int pj = 0; pj < 3; ++pj) {
        f32x4 pacc[4];
#pragma unroll
        for (int nt = 0; nt < 4; ++nt) pacc[nt] = (f32x4){0.f, 0.f, 0.f, 0.f};

#pragma unroll
        for (int nt = 0; nt < 4; ++nt) {
#pragma unroll
            for (int kc = 0; kc < 4; ++kc) {
                bf16x8 aw = *(const bf16x8*)(wlds + (64 * pj + 16 * nt + l15) * 136 +
                                             kc * 32 + quad * 8);
                pacc[nt] = __builtin_amdgcn_mfma_f32_16x16x32_bf16(
                    aw, bxg[kc], pacc[nt], 0, 0, 0);
            }
        }

        if (pj < 2) {
            unsigned short* O = (pj == 0) ? ko : qo;
#pragma unroll
            for (int nt = 0; nt < 4; ++nt) {
                ushort4 h;
                h.x = f2bf(pacc[nt][0]); h.y = f2bf(pacc[nt][1]);
                h.z = f2bf(pacc[nt][2]); h.w = f2bf(pacc[nt][3]);
                *(ushort4*)(O + (size_t)(R0 + m) * HH + 16 * nt + quad * 4) = h;
            }
        } else {
            // C' layout IS vT: lane holds h = 16nt+quad*4+r, t = t0 + m
#pragma unroll
            for (int nt = 0; nt < 4; ++nt) {
                unsigned short* dst =
                    vto + (size_t)b * (HH * TB) + (16 * nt + quad * 4) * TB + t0 + m;
#pragma unroll
                for (int r = 0; r < 4; ++r)
                    dst[r * TB] = f2bf(pacc[nt][r]);
            }
        }
    }
}

// ---- attn: one 64-row q-tile per block, S^T operand swap, no-max softmax ----
__global__ __launch_bounds__(256, 3) void attn_kernel(
    const unsigned short* __restrict__ q, const unsigned short* __restrict__ k,
    const unsigned short* __restrict__ vt, float* __restrict__ out)
{
    __shared__ unsigned short ks[64 * 72];   // K tile, row-major [t][h]
    __shared__ unsigned short vs[64 * 72];   // vT tile, [h][t]
    __shared__ unsigned short ps[64 * 76];   // P round-trip, wave-private rows

    const int tid  = threadIdx.x;
    const int wave = tid >> 6;
    const int lane = tid & 63;
    const int l15  = lane & 15;
    const int quad = lane >> 4;
    const int b    = blockIdx.x;             // 0..127 -> XCD b%8 pinned
    const int qt   = 7 - blockIdx.y;         // longest blocks dispatch first
    const int q0   = qt * 64;
    const size_t base = (size_t)b * TB * HH;

    bf16x8 ones;
#pragma unroll
    for (int i = 0; i < 8; ++i) ones[i] = (short)0x3F80;   // bf16 1.0

    // staging address mapping
    const int r0 = tid >> 3, c8 = (tid & 7) * 8;
    const int r1 = r0 + 32;

    // prefetch kv tile kt=0
    bf16x8 kr0 = *(const bf16x8*)(k + base + (size_t)r0 * HH + c8);
    bf16x8 kr1 = *(const bf16x8*)(k + base + (size_t)r1 * HH + c8);
    bf16x8 vr0 = *(const bf16x8*)(vt + base + (size_t)r0 * TB + c8);
    bf16x8 vr1 = *(const bf16x8*)(vt + base + (size_t)r1 * TB + c8);

    // Q A-frags for this wave's 16 q-rows
    const unsigned short* qr = q + base + (size_t)(q0 + 16 * wave + l15) * HH;
    bf16x8 aq0 = *(const bf16x8*)(qr + quad * 8);
    bf16x8 aq1 = *(const bf16x8*)(qr + 32 + quad * 8);

    f32x4 o[4], lacc;
#pragma unroll
    for (int nt = 0; nt < 4; ++nt) o[nt] = (f32x4){0.f, 0.f, 0.f, 0.f};
    lacc = (f32x4){0.f, 0.f, 0.f, 0.f};

    const int nIt = qt + 1;
    for (int kt = 0; kt < nIt; ++kt) {
        __syncthreads();                     // prev tile's frag reads done
        *(bf16x8*)(ks + r0 * 72 + c8) = kr0;
        *(bf16x8*)(ks + r1 * 72 + c8) = kr1;
        *(bf16x8*)(vs + r0 * 72 + c8) = vr0;
        *(bf16x8*)(vs + r1 * 72 + c8) = vr1;
        __syncthreads();

        if (kt + 1 < nIt) {                  // prefetch next tile
            const int k0n = (kt + 1) * 64;
            kr0 = *(const bf16x8*)(k + base + (size_t)(k0n + r0) * HH + c8);
            kr1 = *(const bf16x8*)(k + base + (size_t)(k0n + r1) * HH + c8);
            vr0 = *(const bf16x8*)(vt + base + (size_t)r0 * TB + k0n + c8);
            vr1 = *(const bf16x8*)(vt + base + (size_t)r1 * TB + k0n + c8);
        }

        // ---- K and V frags ----
        bf16x8 bk0[4], bk1[4], bv0[4], bv1[4];
#pragma unroll
        for (int nt = 0; nt < 4; ++nt) {
            bk0[nt] = *(const bf16x8*)(ks + (16 * nt + l15) * 72 + quad * 8);
            bk1[nt] = *(const bf16x8*)(ks + (16 * nt + l15) * 72 + 32 + quad * 8);
            bv0[nt] = *(const bf16x8*)(vs + (16 * nt + l15) * 72 + quad * 8);
            bv1[nt] = *(const bf16x8*)(vs + (16 * nt + l15) * 72 + 32 + quad * 8);
        }

        // ---- S^T = mfma(K, Q): lane q = 16*wave+l15, k = 16*nt+4*quad+r ----
        f32x4 s[4];
#pragma unroll
        for (int nt = 0; nt < 4; ++nt) {
            f32x4 z = (f32x4){0.f, 0.f, 0.f, 0.f};
            z = __builtin_amdgcn_mfma_f32_16x16x32_bf16(bk0[nt], aq0, z, 0, 0, 0);
            z = __builtin_amdgcn_mfma_f32_16x16x32_bf16(bk1[nt], aq1, z, 0, 0, 0);
            s[nt] = z;
        }

        // ---- scale+mask+exp, P store: 4x ushort4 (k-contiguous per lane) ----
        const bool diag = (kt == qt);
        unsigned short* pr = ps + (16 * wave + l15) * 76;
#pragma unroll
        for (int nt = 0; nt < 4; ++nt) {
            float p[4];
#pragma unroll
            for (int r = 0; r < 4; ++r) {
                float sv = s[nt][r] * SCALE;
                if (diag && (16 * nt + 4 * quad + r) > (16 * wave + l15)) sv = -1e30f;
                p[r] = __expf(sv);
            }
            ushort4 h;
            h.x = f2bf(p[0]); h.y = f2bf(p[1]); h.z = f2bf(p[2]); h.w = f2bf(p[3]);
            *(ushort4*)(pr + 16 * nt + 4 * quad) = h;
        }

        // ---- P A-frags back (same-wave in-order LDS), rowsum + PV ----
        bf16x8 ap0 = *(const bf16x8*)(pr + quad * 8);
        bf16x8 ap1 = *(const bf16x8*)(pr + 32 + quad * 8);
        lacc = __builtin_amdgcn_mfma_f32_16x16x32_bf16(ap0, ones, lacc, 0, 0, 0);
        lacc = __builtin_amdgcn_mfma_f32_16x16x32_bf16(ap1, ones, lacc, 0, 0, 0);
#pragma unroll
        for (int nt = 0; nt < 4; ++nt) {
            o[nt] = __builtin_amdgcn_mfma_f32_16x16x32_bf16(ap0, bv0[nt], o[nt], 0, 0, 0);
            o[nt] = __builtin_amdgcn_mfma_f32_16x16x32_bf16(ap1, bv1[nt], o[nt], 0, 0, 0);
        }
    }

    // ---- epilogue ----
    float inv[4];
#pragma unroll
    for (int r = 0; r < 4; ++r) inv[r] = __builtin_amdgcn_rcpf(lacc[r]);
#pragma unroll
    for (int nt = 0; nt < 4; ++nt)
#pragma unroll
        for (int r = 0; r < 4; ++r)
            out[base + (size_t)(q0 + 16 * wave + quad * 4 + r) * HH + 16 * nt + l15] =
                o[nt][r] * inv[r];
}

extern "C" void kernel_launch(void* const* d_in, const int* in_sizes, int n_in,
                              void* d_out, int out_size, void* d_ws, size_t ws_size,
                              hipStream_t stream) {
    const float* x  = (const float*)d_in[0];
    const float* Wg = (const float*)d_in[1];
    const float* bg = (const float*)d_in[2];
    const float* Wk = (const float*)d_in[3];
    const float* Wq = (const float*)d_in[4];
    const float* Wv = (const float*)d_in[5];
    float* out = (float*)d_out;

    unsigned short* ws = (unsigned short*)d_ws;
    const size_t BTH = (size_t)BB * TB * HH;   // 4,194,304
    unsigned short* qo  = ws;
    unsigned short* ko  = ws + BTH;
    unsigned short* vto = ws + 2 * BTH;
    unsigned short* WgT = ws + 3 * BTH;        // 128x128
    unsigned short* WkT = WgT + 16384;         // 64x128 each
    unsigned short* WqT = WkT + 8192;
    unsigned short* WvT = WqT + 8192;          // total ws: 25.25 MB

    hipLaunchKernelGGL(prep_weights, dim3(160), dim3(256), 0, stream,
                       Wg, Wk, Wq, Wv, WgT, WkT, WqT, WvT);
    hipLaunchKernelGGL(gate_qkv_kernel, dim3(BB * TB / 64), dim3(256), 0, stream,
                       x, bg, WgT, WkT, WqT, WvT, qo, ko, vto);
    hipLaunchKernelGGL(attn_kernel, dim3(BB, 8), dim3(256), 0, stream,
                       qo, ko, vto, out);
}